// Round 3
// baseline (326.877 us; speedup 1.0000x reference)
//
#include <hip/hip_runtime.h>
#include <math.h>

constexpr int B = 128, N = 512, HID = 512, NH = 8, DH = 64;

// ---------------------------------------------------------------------------
// K1: query = w_seed_w*seed + w_seed_b; q = w_q @ query;
//     qk[h][j] = (1/sqrt(DH)) * sum_d q[h*64+d] * w_v[(h*64+d)*HID + j]
// grid 64 (h = bid>>3, jc = bid&7), block 64
// ---------------------------------------------------------------------------
__global__ __launch_bounds__(64) void k1_qk(
    const float* __restrict__ w_q, const float* __restrict__ w_v,
    const float* __restrict__ w_sw, const float* __restrict__ w_sb,
    const float* __restrict__ seed, float* __restrict__ qk)
{
    __shared__ __align__(16) float query_s[HID];
    __shared__ float q_s[DH];
    const int t  = threadIdx.x;
    const int h  = blockIdx.x >> 3;
    const int jc = blockIdx.x & 7;
    const float sv = seed[0];
    #pragma unroll
    for (int k = 0; k < 8; ++k) {
        const int j = t * 8 + k;
        query_s[j] = w_sw[j] * sv + w_sb[j];
    }
    __syncthreads();
    {
        const float* row = w_q + (size_t)(h * DH + t) * HID;
        float acc = 0.f;
        for (int j = 0; j < HID; j += 4) {
            const float4 wv = *(const float4*)(row + j);
            acc += wv.x * query_s[j]     + wv.y * query_s[j + 1]
                 + wv.z * query_s[j + 2] + wv.w * query_s[j + 3];
        }
        q_s[t] = acc;
    }
    __syncthreads();
    {
        const int j = jc * 64 + t;
        float acc = 0.f;
        for (int d = 0; d < DH; ++d)
            acc += q_s[d] * w_v[(size_t)(h * DH + d) * HID + j];
        qk[h * HID + j] = acc * 0.125f;   // fold 1/sqrt(64)
    }
}

// ---------------------------------------------------------------------------
// KA: fully fused per-batch pipeline. grid B, block 512 (8 waves), ~106KB LDS
//   phase1: e[n][h] = <h[b,n,:], qk[h,:]>        (thread = row; uniform guard)
//   phase2: softmax per head (wave = head), write alpha + store a into e_s
//   phase3: ctx[h][j] = sum_n a[n][h]*h[b,n,j]   (thread = (rowquad, col4))
//   phase4: out_h = ctx . w_v rows; out = out_h . w_o rows
// ---------------------------------------------------------------------------
__global__ __launch_bounds__(512) void ka_fused(
    const float* __restrict__ hbuf, const int* __restrict__ lengths,
    const float* __restrict__ qk, const float* __restrict__ w_v,
    const float* __restrict__ w_o, float* __restrict__ out,
    float* __restrict__ alpha)
{
    __shared__ __align__(16) float e_s[N][12];       // 24 KB; 48B rows -> 16B aligned
    __shared__ __align__(16) float part_s[4 * NH * HID]; // 64 KB
    __shared__ __align__(16) float ctx_s[NH * HID];      // 16 KB
    __shared__ __align__(16) float oh_s[HID];            // 2 KB
    const int t   = threadIdx.x;
    const int b   = blockIdx.x;
    const int len = lengths[b];

    // ---- phase 1: logits. Wave-uniform guard so qk loads scalarize. ----
    {
        const int wbase = __builtin_amdgcn_readfirstlane(t) & ~63;
        if (wbase < len) {
            const int n  = t;
            const int nn = min(n, len - 1);          // clamp: uniform control flow
            const float* row = hbuf + ((size_t)b * N + nn) * HID;
            float acc[NH];
            #pragma unroll
            for (int hh = 0; hh < NH; ++hh) acc[hh] = 0.f;
            #pragma unroll 2
            for (int j = 0; j < HID; j += 4) {
                const float4 hv = *(const float4*)(row + j);
                #pragma unroll
                for (int hh = 0; hh < NH; ++hh) {
                    const float* qp = qk + hh * HID + j;   // lane-independent -> s_load
                    acc[hh] += hv.x * qp[0] + hv.y * qp[1]
                             + hv.z * qp[2] + hv.w * qp[3];
                }
            }
            #pragma unroll
            for (int hh = 0; hh < NH; ++hh)
                e_s[n][hh] = (n < len) ? acc[hh] : -3.0e38f;
        }
    }
    __syncthreads();

    // ---- phase 2: masked softmax, wave w = head w ----
    {
        const int lane = t & 63;
        const int w    = t >> 6;
        float ev[8];
        float m = -3.0e38f;
        #pragma unroll
        for (int it = 0; it < 8; ++it) {
            const int n = it * 64 + lane;
            ev[it] = (n < len) ? e_s[n][w] : -3.0e38f;
            m = fmaxf(m, ev[it]);
        }
        #pragma unroll
        for (int off = 32; off; off >>= 1)
            m = fmaxf(m, __shfl_xor(m, off, 64));
        float s = 0.f;
        #pragma unroll
        for (int it = 0; it < 8; ++it) {
            ev[it] = __expf(ev[it] - m);     // invalid -> exp(-huge) = 0
            s += ev[it];
        }
        #pragma unroll
        for (int off = 32; off; off >>= 1)
            s += __shfl_xor(s, off, 64);
        const float inv = 1.f / s;
        float* ao = alpha + (size_t)(b * NH + w) * N;
        #pragma unroll
        for (int it = 0; it < 8; ++it) {
            const int n   = it * 64 + lane;
            const float v = (n < len) ? ev[it] * inv : 0.f;
            ao[n]      = v;                  // coalesced global write
            e_s[n][w]  = v;                  // alpha staged for phase 3
        }
    }
    __syncthreads();

    // ---- phase 3: ctx partials. quad q owns rows n ≡ q (mod 4); col4 = cq ----
    {
        const int q  = t >> 7;               // 0..3
        const int cq = t & 127;              // col quad 0..127
        float4 acc[NH];
        #pragma unroll
        for (int hh = 0; hh < NH; ++hh) { acc[hh].x = acc[hh].y = acc[hh].z = acc[hh].w = 0.f; }
        const float* hb = hbuf + (size_t)b * N * HID + cq * 4;
        for (int n = q; n < len; n += 4) {
            const float4 hv = *(const float4*)(hb + (size_t)n * HID);  // 1KB/wave coalesced
            const float4 a0 = *(const float4*)&e_s[n][0];   // wave-uniform -> broadcast
            const float4 a1 = *(const float4*)&e_s[n][4];
            acc[0].x += a0.x * hv.x; acc[0].y += a0.x * hv.y; acc[0].z += a0.x * hv.z; acc[0].w += a0.x * hv.w;
            acc[1].x += a0.y * hv.x; acc[1].y += a0.y * hv.y; acc[1].z += a0.y * hv.z; acc[1].w += a0.y * hv.w;
            acc[2].x += a0.z * hv.x; acc[2].y += a0.z * hv.y; acc[2].z += a0.z * hv.z; acc[2].w += a0.z * hv.w;
            acc[3].x += a0.w * hv.x; acc[3].y += a0.w * hv.y; acc[3].z += a0.w * hv.z; acc[3].w += a0.w * hv.w;
            acc[4].x += a1.x * hv.x; acc[4].y += a1.x * hv.y; acc[4].z += a1.x * hv.z; acc[4].w += a1.x * hv.w;
            acc[5].x += a1.y * hv.x; acc[5].y += a1.y * hv.y; acc[5].z += a1.y * hv.z; acc[5].w += a1.y * hv.w;
            acc[6].x += a1.z * hv.x; acc[6].y += a1.z * hv.y; acc[6].z += a1.z * hv.z; acc[6].w += a1.z * hv.w;
            acc[7].x += a1.w * hv.x; acc[7].y += a1.w * hv.y; acc[7].z += a1.w * hv.z; acc[7].w += a1.w * hv.w;
        }
        #pragma unroll
        for (int hh = 0; hh < NH; ++hh)
            *(float4*)&part_s[(q * NH + hh) * HID + cq * 4] = acc[hh];
    }
    __syncthreads();

    // ---- combine 4 row-quad partials -> ctx ----
    for (int i = t; i < NH * HID; i += 512)
        ctx_s[i] = part_s[i] + part_s[NH * HID + i]
                 + part_s[2 * NH * HID + i] + part_s[3 * NH * HID + i];
    __syncthreads();

    // ---- phase 4a: out_h[p] = <ctx[p>>6], w_v[p,:]> ----
    {
        const int p  = t;
        const int hh = p >> 6;               // wave-uniform
        const float* wrow = w_v + (size_t)p * HID;
        float acc = 0.f;
        for (int j = 0; j < HID; j += 4) {
            const float4 wv = *(const float4*)(wrow + j);
            const float4 cv = *(const float4*)&ctx_s[hh * HID + j];   // broadcast
            acc += wv.x * cv.x + wv.y * cv.y + wv.z * cv.z + wv.w * cv.w;
        }
        oh_s[p] = acc;
    }
    __syncthreads();

    // ---- phase 4b: out[b,i] = <out_h, w_o[i,:]> ----
    {
        const int i = t;
        const float* wrow = w_o + (size_t)i * HID;
        float acc = 0.f;
        for (int j = 0; j < HID; j += 4) {
            const float4 wv = *(const float4*)(wrow + j);
            const float4 ov = *(const float4*)&oh_s[j];               // broadcast
            acc += wv.x * ov.x + wv.y * ov.y + wv.z * ov.z + wv.w * ov.w;
        }
        out[(size_t)b * HID + i] = acc;
    }
}

// ---------------------------------------------------------------------------
extern "C" void kernel_launch(void* const* d_in, const int* in_sizes, int n_in,
                              void* d_out, int out_size, void* d_ws, size_t ws_size,
                              hipStream_t stream) {
    const float* h     = (const float*)d_in[0];
    const int*   lens  = (const int*)  d_in[1];
    const float* w_q   = (const float*)d_in[2];
    // d_in[3] = w_k: dead compute in the reference, intentionally unused
    const float* w_v   = (const float*)d_in[4];
    const float* w_o   = (const float*)d_in[5];
    const float* w_sw  = (const float*)d_in[6];
    const float* w_sb  = (const float*)d_in[7];
    const float* seed  = (const float*)d_in[8];

    float* out   = (float*)d_out;            // [B, HID]
    float* alpha = out + (size_t)B * HID;    // [B, NH, N, 1]

    float* qk = (float*)d_ws;                // only 16 KB of ws used now

    hipLaunchKernelGGL(k1_qk,    dim3(64), dim3(64),  0, stream,
                       w_q, w_v, w_sw, w_sb, seed, qk);
    hipLaunchKernelGGL(ka_fused, dim3(B),  dim3(512), 0, stream,
                       h, lens, qk, w_v, w_o, out, alpha);
}